// Round 3
// baseline (663.320 us; speedup 1.0000x reference)
//
#include <hip/hip_runtime.h>
#include <hip/hip_bf16.h>

#define EMB 1024
#define HEADS 16
#define HDIM 64
#define FFDIM 4096
#define BSZ 4
#define SEQ 2048
#define MROWS (BSZ * SEQ)

typedef __attribute__((ext_vector_type(8))) short bf16x8;
typedef __attribute__((ext_vector_type(4))) float f32x4;
typedef __attribute__((ext_vector_type(4))) unsigned short u16x4;
typedef unsigned short u16;

__device__ __forceinline__ float bf2f(u16 u) {
  union { unsigned int i; float f; } c; c.i = ((unsigned int)u) << 16; return c.f;
}
__device__ __forceinline__ u16 f2bf(float f) {
  union { float f; unsigned int i; } c; c.f = f;
  unsigned int i = c.i + 0x7fff + ((c.i >> 16) & 1);
  return (u16)(i >> 16);
}

// ---- LayerNorm: f32 in -> bf16 out, one wave per row (4 rows/block) ------
__global__ __launch_bounds__(256) void ln_kernel(
    const float* __restrict__ x, const float* __restrict__ g,
    const float* __restrict__ be, u16* __restrict__ out) {
  int w = threadIdx.x >> 6, l = threadIdx.x & 63;
  size_t row = (size_t)blockIdx.x * 4 + w;
  const float* xr = x + row * EMB;
  float f[4][4];
  float s = 0.f, s2 = 0.f;
#pragma unroll
  for (int c = 0; c < 4; ++c) {
    f32x4 v = *(const f32x4*)(xr + c * 256 + l * 4);
#pragma unroll
    for (int j = 0; j < 4; ++j) {
      f[c][j] = v[j];
      s += v[j];
      s2 += v[j] * v[j];
    }
  }
#pragma unroll
  for (int m = 1; m < 64; m <<= 1) {
    s  += __shfl_xor(s, m);
    s2 += __shfl_xor(s2, m);
  }
  float mu = s * (1.f / EMB);
  float var = s2 * (1.f / EMB) - mu * mu;
  float rs = rsqrtf(var + 1e-5f);
#pragma unroll
  for (int c = 0; c < 4; ++c) {
    u16x4 o;
#pragma unroll
    for (int j = 0; j < 4; ++j) {
      int col = c * 256 + l * 4 + j;
      o[j] = f2bf((f[c][j] - mu) * rs * g[col] + be[col]);
    }
    *(u16x4*)(out + row * EMB + c * 256 + l * 4) = o;
  }
}

// ---- convert+transpose: f32 [R][C] -> bf16 [C][R] ------------------------
__global__ __launch_bounds__(256) void transpose_cvt(
    const float* __restrict__ in, u16* __restrict__ out, int R, int C) {
  __shared__ u16 tile[32][33];
  int c0 = blockIdx.x * 32, r0 = blockIdx.y * 32;
  int tx = threadIdx.x, ty = threadIdx.y;
#pragma unroll
  for (int i = ty; i < 32; i += 8)
    tile[i][tx] = f2bf(in[(size_t)(r0 + i) * C + c0 + tx]);
  __syncthreads();
#pragma unroll
  for (int i = ty; i < 32; i += 8)
    out[(size_t)(c0 + i) * R + r0 + tx] = tile[tx][i];
}

// ---- GEMM: A[M,K]bf16 x Bt[N,K]bf16 + bias(f32) (+gelu / +res f32) -------
__device__ __forceinline__ float gelu_f(float v) {
  float inner = 0.7978845608028654f * (v + 0.044715f * v * v * v);
  return 0.5f * v * (1.f + tanhf(inner));
}

template <int EPI, typename OT>  // bit0: +res, bit1: gelu
__global__ __launch_bounds__(256) void gemm_bt(
    const u16* __restrict__ A, const u16* __restrict__ Bt,
    const float* __restrict__ bias, const float* __restrict__ res,
    OT* __restrict__ C, int N, int K) {
  __shared__ u16 As[128 * 32];
  __shared__ u16 Bs[128 * 32];
  int nb = N >> 7;
  int mb = blockIdx.x / nb, nbi = blockIdx.x % nb;
  int m0 = mb << 7, n0 = nbi << 7;
  int t = threadIdx.x, l = t & 63, lg = l >> 4, lc = l & 15;
  int w = t >> 6;
  int wr = w >> 1, wc = w & 1;
  f32x4 acc[4][4] = {};
  int sr = t >> 2, sc = (t & 3) * 8;
  const u16* Ag = A + (size_t)(m0 + sr) * K + sc;
  const u16* Bg = Bt + (size_t)(n0 + sr) * K + sc;
  for (int k0 = 0; k0 < K; k0 += 32) {
    bf16x8 va0 = *(const bf16x8*)(Ag + k0);
    bf16x8 va1 = *(const bf16x8*)(Ag + k0 + (size_t)64 * K);
    bf16x8 vb0 = *(const bf16x8*)(Bg + k0);
    bf16x8 vb1 = *(const bf16x8*)(Bg + k0 + (size_t)64 * K);
    __syncthreads();  // previous iteration's LDS reads complete
    *(bf16x8*)(As + sr * 32 + sc) = va0;
    *(bf16x8*)(As + (sr + 64) * 32 + sc) = va1;
    *(bf16x8*)(Bs + sr * 32 + sc) = vb0;
    *(bf16x8*)(Bs + (sr + 64) * 32 + sc) = vb1;
    __syncthreads();
    bf16x8 af[4], bfv[4];
#pragma unroll
    for (int i = 0; i < 4; ++i)
      af[i] = *(const bf16x8*)(As + (wr * 64 + i * 16 + lc) * 32 + lg * 8);
#pragma unroll
    for (int j = 0; j < 4; ++j)
      bfv[j] = *(const bf16x8*)(Bs + (wc * 64 + j * 16 + lc) * 32 + lg * 8);
#pragma unroll
    for (int i = 0; i < 4; ++i)
#pragma unroll
      for (int j = 0; j < 4; ++j)
        acc[i][j] = __builtin_amdgcn_mfma_f32_16x16x32_bf16(af[i], bfv[j], acc[i][j], 0, 0, 0);
  }
#pragma unroll
  for (int i = 0; i < 4; ++i)
#pragma unroll
    for (int j = 0; j < 4; ++j) {
      int col = n0 + wc * 64 + j * 16 + lc;
      float bcol = bias[col];
#pragma unroll
      for (int r = 0; r < 4; ++r) {
        int row = m0 + wr * 64 + i * 16 + lg * 4 + r;
        float v = acc[i][j][r] + bcol;
        if (EPI & 2) v = gelu_f(v);
        if (EPI & 1) v += res[(size_t)row * N + col];
        if (sizeof(OT) == 2)
          C[(size_t)row * N + col] = (OT)f2bf(v);
        else
          C[(size_t)row * N + col] = (OT)v;
      }
    }
}

// ---- causal flash attention (bf16): 1 wave per 16 q-rows -----------------
__global__ __launch_bounds__(64) void attn_kernel(
    const u16* __restrict__ Q, const u16* __restrict__ Kin,
    const u16* __restrict__ V, u16* __restrict__ O) {
  __shared__ u16 lds_p[16 * 32];
  int l = threadIdx.x, lg = l >> 4, lc = l & 15;
  int nq = SEQ / 16;
  int qt = blockIdx.x % nq, bh = blockIdx.x / nq;
  int h = bh % HEADS, b = bh / HEADS;
  int q0 = qt * 16;
  const u16* Qp = Q + (size_t)b * SEQ * EMB + h * HDIM;
  const u16* Kp = Kin + (size_t)b * SEQ * EMB + h * HDIM;
  const u16* Vp = V + (size_t)b * SEQ * EMB + h * HDIM;
  u16* Op = O + (size_t)b * SEQ * EMB + h * HDIM;

  bf16x8 aq0 = *(const bf16x8*)(Qp + (size_t)(q0 + lc) * EMB + lg * 8);
  bf16x8 aq1 = *(const bf16x8*)(Qp + (size_t)(q0 + lc) * EMB + 32 + lg * 8);

  f32x4 acc[4] = {};
  float mrow[4], lrow[4];
#pragma unroll
  for (int r = 0; r < 4; ++r) { mrow[r] = -1e30f; lrow[r] = 0.f; }

  for (int kv0 = 0; kv0 <= q0 + 15; kv0 += 32) {
    f32x4 s0 = {0.f, 0.f, 0.f, 0.f}, s1 = {0.f, 0.f, 0.f, 0.f};
    bf16x8 bk;
    bk = *(const bf16x8*)(Kp + (size_t)(kv0 + lc) * EMB + lg * 8);
    s0 = __builtin_amdgcn_mfma_f32_16x16x32_bf16(aq0, bk, s0, 0, 0, 0);
    bk = *(const bf16x8*)(Kp + (size_t)(kv0 + lc) * EMB + 32 + lg * 8);
    s0 = __builtin_amdgcn_mfma_f32_16x16x32_bf16(aq1, bk, s0, 0, 0, 0);
    bk = *(const bf16x8*)(Kp + (size_t)(kv0 + 16 + lc) * EMB + lg * 8);
    s1 = __builtin_amdgcn_mfma_f32_16x16x32_bf16(aq0, bk, s1, 0, 0, 0);
    bk = *(const bf16x8*)(Kp + (size_t)(kv0 + 16 + lc) * EMB + 32 + lg * 8);
    s1 = __builtin_amdgcn_mfma_f32_16x16x32_bf16(aq1, bk, s1, 0, 0, 0);

    __syncthreads();
    float p0[4], p1[4];
#pragma unroll
    for (int r = 0; r < 4; ++r) {
      int row = q0 + lg * 4 + r;
      float v0 = s0[r] * 0.125f;
      float v1 = s1[r] * 0.125f;
      if (kv0 + lc > row) v0 = -1e30f;
      if (kv0 + 16 + lc > row) v1 = -1e30f;
      float tm = fmaxf(v0, v1);
#pragma unroll
      for (int mm = 1; mm < 16; mm <<= 1) tm = fmaxf(tm, __shfl_xor(tm, mm));
      float nm = fmaxf(mrow[r], tm);
      float e0 = __expf(v0 - nm);
      float e1 = __expf(v1 - nm);
      float ts = e0 + e1;
#pragma unroll
      for (int mm = 1; mm < 16; mm <<= 1) ts += __shfl_xor(ts, mm);
      float sc = __expf(mrow[r] - nm);
      lrow[r] = lrow[r] * sc + ts;
      mrow[r] = nm;
#pragma unroll
      for (int dc = 0; dc < 4; ++dc) acc[dc][r] *= sc;
      p0[r] = e0; p1[r] = e1;
    }
#pragma unroll
    for (int r = 0; r < 4; ++r) {
      lds_p[(lg * 4 + r) * 32 + lc] = f2bf(p0[r]);
      lds_p[(lg * 4 + r) * 32 + 16 + lc] = f2bf(p1[r]);
    }
    __syncthreads();
    bf16x8 ap = *(const bf16x8*)(lds_p + lc * 32 + lg * 8);
#pragma unroll
    for (int dc = 0; dc < 4; ++dc) {
      bf16x8 bv;
#pragma unroll
      for (int j = 0; j < 8; ++j)
        bv[j] = (short)Vp[(size_t)(kv0 + lg * 8 + j) * EMB + dc * 16 + lc];
      acc[dc] = __builtin_amdgcn_mfma_f32_16x16x32_bf16(ap, bv, acc[dc], 0, 0, 0);
    }
  }
#pragma unroll
  for (int dc = 0; dc < 4; ++dc)
#pragma unroll
    for (int r = 0; r < 4; ++r) {
      int row = q0 + lg * 4 + r;
      Op[(size_t)row * EMB + dc * 16 + lc] = f2bf(acc[dc][r] / lrow[r]);
    }
}

// ---- driver ---------------------------------------------------------------
extern "C" void kernel_launch(void* const* d_in, const int* in_sizes, int n_in,
                              void* d_out, int out_size, void* d_ws, size_t ws_size,
                              hipStream_t stream) {
  (void)in_sizes; (void)n_in; (void)out_size; (void)ws_size;
  const float* x   = (const float*)d_in[0];
  const float* Wq  = (const float*)d_in[1];
  const float* bq  = (const float*)d_in[2];
  const float* Wk  = (const float*)d_in[3];
  const float* bk  = (const float*)d_in[4];
  const float* Wv  = (const float*)d_in[5];
  const float* bv  = (const float*)d_in[6];
  const float* Wo  = (const float*)d_in[7];
  const float* bo  = (const float*)d_in[8];
  const float* W1  = (const float*)d_in[9];
  const float* b1  = (const float*)d_in[10];
  const float* W2  = (const float*)d_in[11];
  const float* b2  = (const float*)d_in[12];
  const float* g1  = (const float*)d_in[13];
  const float* be1 = (const float*)d_in[14];
  const float* g2  = (const float*)d_in[15];
  const float* be2 = (const float*)d_in[16];

  char* ws = (char*)d_ws;
  const size_t MB = 1ull << 20;
  u16*   WqT  = (u16*)(ws + 0 * MB);     // 2 MB
  u16*   WkT  = (u16*)(ws + 2 * MB);     // 2 MB
  u16*   WvT  = (u16*)(ws + 4 * MB);     // 2 MB
  u16*   WoT  = (u16*)(ws + 6 * MB);     // 2 MB
  u16*   W1T  = (u16*)(ws + 8 * MB);     // 8 MB
  u16*   W2T  = (u16*)(ws + 16 * MB);    // 8 MB
  u16*   hbuf = (u16*)(ws + 24 * MB);    // 16 MB: LN1 out, later ctx
  u16*   Kbuf = (u16*)(ws + 40 * MB);    // 16 MB: K, later h2
  float* x1f  = (float*)(ws + 56 * MB);  // 32 MB: attn residual out (f32)
  u16*   Qbuf = (u16*)(ws + 88 * MB);    // 16 MB: Q (dead after attn)
  u16*   Vbuf = (u16*)(ws + 104 * MB);   // 16 MB: V (dead after attn)
  u16*   gbuf = (u16*)(ws + 88 * MB);    // 64 MB: FF1 out (overlaps dead Q,V)

  dim3 tb(32, 8);
  transpose_cvt<<<dim3(EMB / 32, EMB / 32), tb, 0, stream>>>(Wq, WqT, EMB, EMB);
  transpose_cvt<<<dim3(EMB / 32, EMB / 32), tb, 0, stream>>>(Wk, WkT, EMB, EMB);
  transpose_cvt<<<dim3(EMB / 32, EMB / 32), tb, 0, stream>>>(Wv, WvT, EMB, EMB);
  transpose_cvt<<<dim3(EMB / 32, EMB / 32), tb, 0, stream>>>(Wo, WoT, EMB, EMB);
  transpose_cvt<<<dim3(FFDIM / 32, EMB / 32), tb, 0, stream>>>(W1, W1T, EMB, FFDIM);
  transpose_cvt<<<dim3(EMB / 32, FFDIM / 32), tb, 0, stream>>>(W2, W2T, FFDIM, EMB);

  ln_kernel<<<MROWS / 4, 256, 0, stream>>>(x, g1, be1, hbuf);

  const int GQKV = (MROWS / 128) * (EMB / 128);    // 512
  const int GFF1 = (MROWS / 128) * (FFDIM / 128);  // 2048
  gemm_bt<0, u16><<<GQKV, 256, 0, stream>>>(hbuf, WqT, bq, nullptr, Qbuf, EMB, EMB);
  gemm_bt<0, u16><<<GQKV, 256, 0, stream>>>(hbuf, WkT, bk, nullptr, Kbuf, EMB, EMB);
  gemm_bt<0, u16><<<GQKV, 256, 0, stream>>>(hbuf, WvT, bv, nullptr, Vbuf, EMB, EMB);

  attn_kernel<<<BSZ * HEADS * (SEQ / 16), 64, 0, stream>>>(Qbuf, Kbuf, Vbuf, hbuf);

  gemm_bt<1, float><<<GQKV, 256, 0, stream>>>(hbuf, WoT, bo, x, x1f, EMB, EMB);

  ln_kernel<<<MROWS / 4, 256, 0, stream>>>(x1f, g2, be2, Kbuf);

  gemm_bt<2, u16><<<GFF1, 256, 0, stream>>>(Kbuf, W1T, b1, nullptr, gbuf, FFDIM, EMB);
  gemm_bt<1, float><<<GQKV, 256, 0, stream>>>(gbuf, W2T, b2, x1f, (float*)d_out, EMB, FFDIM);
}